// Round 6
// baseline (1909.212 us; speedup 1.0000x reference)
//
#include <hip/hip_runtime.h>
#include <stdint.h>

#define N_TOK 4096
#define DIM_IN 512
#define NH 12
#define HD 64
#define CDIM 768   // NH*HD

using f32x4  = __attribute__((ext_vector_type(4))) float;
using f32x16 = __attribute__((ext_vector_type(16))) float;
using bf16x8 = __attribute__((ext_vector_type(8))) short;

static __device__ __forceinline__ unsigned short f2bf(float f){
    union { float f; unsigned int u; } v; v.f = f;
    unsigned int r = v.u + 0x7fffu + ((v.u >> 16) & 1u);
    return (unsigned short)(r >> 16);
}

// ---------------------------------------------------------------------------
// proj: out[n][c] = (sum_d g[n][d]*W[c][d] + B[c]) * (scale ? scale[c/64] : 1)
// stored as bf16, BOTH row-major (out) and transposed (outT[c][n]).
// outT feeds bwd phase B with contiguous column reads (kills the u16 gather).
// ---------------------------------------------------------------------------
__global__ __launch_bounds__(256) void proj_kernel(
    const float* __restrict__ g, const float* __restrict__ W,
    const float* __restrict__ B, const float* __restrict__ scale,
    unsigned short* __restrict__ out, unsigned short* __restrict__ outT)
{
    __shared__ float at[16][68];
    __shared__ float bt[16][68];
    const int n0 = blockIdx.x * 64, c0 = blockIdx.y * 64;
    const int t  = threadIdx.x;
    const int tx = t & 15, ty = t >> 4;
    const int lr = t >> 2, lk = (t & 3) * 4;
    float acc[4][4] = {};
    for (int d0 = 0; d0 < DIM_IN; d0 += 16){
        __syncthreads();
        f32x4 gv = *(const f32x4*)&g[(size_t)(n0 + lr) * DIM_IN + d0 + lk];
        at[lk+0][lr] = gv[0]; at[lk+1][lr] = gv[1]; at[lk+2][lr] = gv[2]; at[lk+3][lr] = gv[3];
        f32x4 wv = *(const f32x4*)&W[(size_t)(c0 + lr) * DIM_IN + d0 + lk];
        bt[lk+0][lr] = wv[0]; bt[lk+1][lr] = wv[1]; bt[lk+2][lr] = wv[2]; bt[lk+3][lr] = wv[3];
        __syncthreads();
        #pragma unroll
        for (int kk = 0; kk < 16; kk++){
            f32x4 av = *(const f32x4*)&at[kk][ty*4];
            f32x4 bv = *(const f32x4*)&bt[kk][tx*4];
            #pragma unroll
            for (int i = 0; i < 4; i++)
                #pragma unroll
                for (int j = 0; j < 4; j++)
                    acc[i][j] += av[i] * bv[j];
        }
    }
    #pragma unroll
    for (int i = 0; i < 4; i++){
        const int n = n0 + ty*4 + i;
        #pragma unroll
        for (int j = 0; j < 4; j++){
            const int c = c0 + tx*4 + j;
            float v = acc[i][j] + B[c];
            if (scale) v *= scale[c >> 6];
            const unsigned short b = f2bf(v);
            out [(size_t)n * CDIM  + c] = b;
            outT[(size_t)c * N_TOK + n] = b;
        }
    }
}

// ---------------------------------------------------------------------------
// forward: per 16x16 (q,k) MFMA tile, 12 head scores -> Hw mix -> adj mask ->
// accumulate sum(exp) per (q-row, h').  atomicAdd partials into l_ws.
// r6: kbuf + per-chunk barriers DELETED.  B-frags read straight from Kh
// (identical bytes, L2-hot: every blockIdx.x shares the k-tiles).  Waves
// free-run -> no lockstep barrier stalls.  adj loaded at k-step top so its
// HBM latency is covered by the 12-head MFMA+mix.
// ---------------------------------------------------------------------------
__global__ __launch_bounds__(256, 2) void fwd_kernel(
    const unsigned short* __restrict__ Qb, const unsigned short* __restrict__ Kh,
    const float* __restrict__ adj, const float* __restrict__ HwG,
    float* __restrict__ l_ws, int seg_len)
{
    __shared__ float hw[NH][12];
    const int t = threadIdx.x;
    if (t < NH * 12) hw[t / 12][t % 12] = HwG[t];
    const int lane = t & 63, wave = t >> 6;
    const int quad = lane >> 4, col = lane & 15;
    const int qt0 = blockIdx.x * 64 + wave * 16;
    const int kstart = blockIdx.y * seg_len;
    __syncthreads();

    bf16x8 af[NH][2];
    {
        const int arow = qt0 + col;
        #pragma unroll
        for (int h = 0; h < NH; h++)
            #pragma unroll
            for (int kk = 0; kk < 2; kk++)
                af[h][kk] = *(const bf16x8*)&Qb[(size_t)arow * CDIM + h*HD + kk*32 + quad*8];
    }
    f32x4 l4[4][3];
    #pragma unroll
    for (int r = 0; r < 4; r++)
        #pragma unroll
        for (int j = 0; j < 3; j++)
            l4[r][j] = (f32x4){0.f,0.f,0.f,0.f};

    for (int k0 = kstart; k0 < kstart + seg_len; k0 += 16){
        // adj for this k-step, issued before the MFMA block (latency cover)
        float av[4];
        #pragma unroll
        for (int r = 0; r < 4; r++)
            av[r] = adj[(size_t)(qt0 + quad*4 + r) * N_TOK + k0 + col];

        const unsigned short* kp = &Kh[(size_t)(k0 + col) * CDIM + quad*8];
        f32x4 tv[4][3];
        #pragma unroll
        for (int r = 0; r < 4; r++)
            #pragma unroll
            for (int j = 0; j < 3; j++)
                tv[r][j] = (f32x4){0.f,0.f,0.f,0.f};
        #pragma unroll
        for (int h = 0; h < NH; h++){
            bf16x8 b0 = *(const bf16x8*)&kp[h*HD];
            bf16x8 b1 = *(const bf16x8*)&kp[h*HD + 32];
            f32x4 s = {0.f,0.f,0.f,0.f};
            s = __builtin_amdgcn_mfma_f32_16x16x32_bf16(af[h][0], b0, s, 0, 0, 0);
            s = __builtin_amdgcn_mfma_f32_16x16x32_bf16(af[h][1], b1, s, 0, 0, 0);
            f32x4 w0 = *(const f32x4*)&hw[h][0];
            f32x4 w1 = *(const f32x4*)&hw[h][4];
            f32x4 w2 = *(const f32x4*)&hw[h][8];
            #pragma unroll
            for (int r = 0; r < 4; r++){
                tv[r][0] += s[r] * w0;
                tv[r][1] += s[r] * w1;
                tv[r][2] += s[r] * w2;
            }
        }
        #pragma unroll
        for (int r = 0; r < 4; r++){
            #pragma unroll
            for (int j = 0; j < 3; j++){
                #pragma unroll
                for (int c = 0; c < 4; c++){
                    const float mm = tv[r][j][c] * av[r];   // matches T*adj
                    if (mm != 0.f) l4[r][j][c] += __expf(mm);
                }
            }
        }
    }
    #pragma unroll
    for (int r = 0; r < 4; r++)
        #pragma unroll
        for (int j = 0; j < 3; j++)
            #pragma unroll
            for (int c = 0; c < 4; c++){
                float v = l4[r][j][c];
                v += __shfl_xor(v, 1, 16);
                v += __shfl_xor(v, 2, 16);
                v += __shfl_xor(v, 4, 16);
                v += __shfl_xor(v, 8, 16);
                if (col == j*4 + c)
                    atomicAdd(&l_ws[(size_t)(qt0 + quad*4 + r) * NH + (j*4 + c)], v);
            }
}

// ---------------------------------------------------------------------------
// lse + energy
// ---------------------------------------------------------------------------
__global__ __launch_bounds__(256) void lse_energy_kernel(
    const float* __restrict__ l_ws, float* __restrict__ lse_ws,
    const float* __restrict__ betas, float* __restrict__ energy)
{
    const int t = threadIdx.x;
    const int i = blockIdx.x * 256 + t;
    const float l = l_ws[i];
    float lse, ep;
    if (l > 0.f){ lse = logf(l); ep = -(1.f / betas[i % NH]) * lse; }
    else        { lse = -1e30f; ep = 0.f; }
    lse_ws[i] = lse;
    __shared__ float red[256];
    red[t] = ep;
    __syncthreads();
    for (int s = 128; s > 0; s >>= 1){
        if (t < s) red[t] += red[t + s];
        __syncthreads();
    }
    if (t == 0) atomicAdd(energy, red[0]);
}

// ---------------------------------------------------------------------------
// backward r6: colbuf/staging/pcol DELETED.
//  - phase A B-frags from colmat global (same bytes colbuf held; L2-hot tile
//    shared by all 128 row-blocks).  A-frags from rowmat (laundered ptr, r4).
//  - phase B B-frags from colmatT global: contiguous b128 column reads --
//    the 96 ds_read_u16 transpose gather is GONE.  A-frags from dsbuf (LDS,
//    r5-verified swizzle).
//  - 2 barriers/chunk: phaseA -> alpha(dsbuf ready) -> {mode1 next-chunk
//    adj/lse loads; phase B MFMAs; mode1 LDS writes} -> beta(dsbuf free,
//    next adj/lse ready).  mode1 adj/lse double-buffered; mode0 reads adj
//    direct (coalesced rows) and per-block rowlse.
//  - LDS 74.9 KB; regs ~200 <= 256 cap (2 waves/EU).  KS=2 (halves final_dg
//    partial traffic; bwd work identical).
// ---------------------------------------------------------------------------
template<int MODE>
__global__ __attribute__((amdgpu_flat_work_group_size(512, 512), amdgpu_waves_per_eu(2, 2)))
void bwd_kernel(
    const unsigned short* __restrict__ rowmat, const unsigned short* __restrict__ colmat,
    const unsigned short* __restrict__ colmatT,
    const float* __restrict__ adj, const float* __restrict__ HwG,
    const float* __restrict__ lse_ws, const float* __restrict__ betas,
    float* __restrict__ out_part, int seg_len)
{
    __shared__ unsigned short dsbuf[NH][32][64];   // 49152 B
    __shared__ float adjbuf[2][32][68];            // 17408 B (mode 1)
    __shared__ float lsebuf[2][64 * NH];           //  6144 B (mode 1)
    __shared__ float rowlse[32 * NH];              //  1536 B (mode 0)
    __shared__ float invbuf[NH];                   //    48 B
    __shared__ float hw[NH][12];                   //   576 B
    const int t = threadIdx.x;
    if (t < NH * 12) hw[t / 12][t % 12] = HwG[t];
    if (t < NH) invbuf[t] = 1.f / betas[t];
    const int lane = t & 63, wave = t >> 6;
    const int quad = lane >> 4, col = lane & 15;
    const int rsub = wave >> 2, csub = wave & 3;
    const int n0 = csub * 16;
    const int rt0 = blockIdx.x * 32;
    const int rbase = rt0 + rsub * 16;       // this wave's 16 rows (phase A)
    const int cstart = blockIdx.y * seg_len;
    const int tA = n0 + col;

    if (MODE == 0 && t < 96)
        *(f32x4*)&rowlse[t*4] = *(const f32x4*)&lse_ws[(size_t)rt0 * NH + t*4];

    // mode-1 adj/lse staging thread mapping (512 threads cover 64q x 32k / 4)
    const int s_qr = t >> 3, s_kc = (t & 7) * 4;
    if (MODE == 1){
        f32x4 a = *(const f32x4*)&adj[(size_t)(cstart + s_qr) * N_TOK + rt0 + s_kc];
        adjbuf[0][s_kc+0][s_qr] = a[0]; adjbuf[0][s_kc+1][s_qr] = a[1];
        adjbuf[0][s_kc+2][s_qr] = a[2]; adjbuf[0][s_kc+3][s_qr] = a[3];
        if (t < 192)
            *(f32x4*)&lsebuf[0][t*4] = *(const f32x4*)&lse_ws[(size_t)cstart * NH + t*4];
    }

    // A-fragment source row for this lane (16 B aligned vector loads)
    const unsigned short* rowp = &rowmat[(size_t)(rbase + col) * CDIM + quad*8];

    f32x16 accB32[3];
    #pragma unroll
    for (int gg = 0; gg < 3; gg++)
        #pragma unroll
        for (int q = 0; q < 16; q++) accB32[gg][q] = 0.f;

    __syncthreads();   // prologue: hw/invbuf/rowlse/buf0 ready

    int pb = 0;
    for (int cb = cstart; cb < cstart + seg_len; cb += 64){
        // ---- phase A: 16 rows x 16 cols; B straight from colmat (global) ----
        {
            // mode-0 adj: direct coalesced loads, issued before the MFMA block
            float av4[4];
            if (MODE == 0){
                #pragma unroll
                for (int r = 0; r < 4; r++)
                    av4[r] = adj[(size_t)(rbase + quad*4 + r) * N_TOK + cb + tA];
            }
            // launder rowmat ptr: block hoisting of loop-invariant A-frag loads
            const unsigned short* rp = rowp;
            asm volatile("" : "+v"(rp));
            const unsigned short* cp = &colmat[(size_t)(cb + tA) * CDIM + quad*8];

            f32x4 G[4][3];
            #pragma unroll
            for (int r = 0; r < 4; r++)
                #pragma unroll
                for (int j = 0; j < 3; j++)
                    G[r][j] = (f32x4){0.f,0.f,0.f,0.f};
            #pragma unroll
            for (int h = 0; h < NH; h++){
                bf16x8 a0 = *(const bf16x8*)&rp[h*HD];
                bf16x8 a1 = *(const bf16x8*)&rp[h*HD + 32];
                bf16x8 b0 = *(const bf16x8*)&cp[h*HD];
                bf16x8 b1 = *(const bf16x8*)&cp[h*HD + 32];
                f32x4 s = {0.f,0.f,0.f,0.f};
                s = __builtin_amdgcn_mfma_f32_16x16x32_bf16(a0, b0, s, 0, 0, 0);
                s = __builtin_amdgcn_mfma_f32_16x16x32_bf16(a1, b1, s, 0, 0, 0);
                f32x4 w0 = *(const f32x4*)&hw[h][0];
                f32x4 w1 = *(const f32x4*)&hw[h][4];
                f32x4 w2 = *(const f32x4*)&hw[h][8];
                #pragma unroll
                for (int r = 0; r < 4; r++){
                    G[r][0] += s[r] * w0;
                    G[r][1] += s[r] * w1;
                    G[r][2] += s[r] * w2;
                }
            }
            // t-values -> gradient G = -(1/b')*P
            #pragma unroll
            for (int r = 0; r < 4; r++){
                const float adjv = (MODE == 0) ? av4[r]
                                  : adjbuf[pb][rsub*16 + quad*4 + r][tA];
                #pragma unroll
                for (int j = 0; j < 3; j++){
                    f32x4 lv;
                    if (MODE == 0) lv = *(const f32x4*)&rowlse[(rsub*16 + quad*4 + r) * NH + j*4];
                    else           lv = *(const f32x4*)&lsebuf[pb][tA * NH + j*4];
                    #pragma unroll
                    for (int c = 0; c < 4; c++){
                        const float mm = G[r][j][c] * adjv;
                        const float p  = (mm != 0.f) ? __expf(mm - lv[c]) : 0.f;
                        G[r][j][c] = -invbuf[j*4 + c] * p;
                    }
                }
            }
            // dS = G @ Hw^T, bf16 into dsbuf (swizzled, r5-verified)
            #pragma unroll
            for (int h = 0; h < NH; h++){
                f32x4 w0 = *(const f32x4*)&hw[h][0];
                f32x4 w1 = *(const f32x4*)&hw[h][4];
                f32x4 w2 = *(const f32x4*)&hw[h][8];
                #pragma unroll
                for (int r = 0; r < 4; r++){
                    f32x4 pr = G[r][0]*w0 + G[r][1]*w1 + G[r][2]*w2;
                    const float d = pr[0] + pr[1] + pr[2] + pr[3];
                    const int m = rsub*16 + quad*4 + r;
                    dsbuf[h][m][tA ^ ((m & 7) << 3)] = f2bf(d);
                }
            }
        }
        __syncthreads();   // alpha: dsbuf ready; adjbuf[pb]/lsebuf[pb] consumed

        // ---- phase B region ----
        // mode-1: issue next chunk's adj/lse loads FIRST (latency under MFMAs)
        f32x4 nadj = {0.f,0.f,0.f,0.f}, nlse = {0.f,0.f,0.f,0.f};
        if (MODE == 1){
            const int nxt = cb + 64;
            const int cbn = (nxt < cstart + seg_len) ? nxt : cstart;  // clamped dummy
            nadj = *(const f32x4*)&adj[(size_t)(cbn + s_qr) * N_TOK + rt0 + s_kc];
            if (t < 192) nlse = *(const f32x4*)&lse_ws[(size_t)cbn * NH + t*4];
        }
        // phase B (32x32x16): dRow[m][z] += sum_kk dS[m][kk]*colmat[kk][z]
        {
            const int mB = lane & 31;
            const int halfB = lane >> 5;
            #pragma unroll
            for (int gg = 0; gg < 3; gg++){
                const int gidx = wave + gg*8;
                const int h = gidx >> 1, cg = gidx & 1;
                const unsigned short* bpT =
                    &colmatT[(size_t)(h*HD + cg*32 + mB) * N_TOK + cb + halfB*8];
                f32x16 acc = accB32[gg];
                #pragma unroll
                for (int k0 = 0; k0 < 64; k0 += 16){
                    const int kbase = k0 + halfB*8;
                    bf16x8 a = *(const bf16x8*)&dsbuf[h][mB][kbase ^ ((mB & 7) << 3)];
                    bf16x8 b = *(const bf16x8*)&bpT[k0];
                    acc = __builtin_amdgcn_mfma_f32_32x32x16_bf16(a, b, acc, 0, 0, 0);
                }
                accB32[gg] = acc;
            }
        }
        // mode-1: write next chunk's adj/lse into the other buffer (LAST)
        if (MODE == 1){
            adjbuf[pb^1][s_kc+0][s_qr] = nadj[0]; adjbuf[pb^1][s_kc+1][s_qr] = nadj[1];
            adjbuf[pb^1][s_kc+2][s_qr] = nadj[2]; adjbuf[pb^1][s_kc+3][s_qr] = nadj[3];
            if (t < 192) *(f32x4*)&lsebuf[pb^1][t*4] = nlse;
        }
        __syncthreads();   // beta: dsbuf free; adjbuf[pb^1]/lsebuf[pb^1] ready
        pb ^= 1;
    }
    // ---- write dRow partials (32x32 D layout, r5-verified) ----
    float* outp = out_part + (size_t)blockIdx.y * N_TOK * CDIM;
    #pragma unroll
    for (int gg = 0; gg < 3; gg++){
        const int gidx = wave + gg*8;
        const int h = gidx >> 1, cg = gidx & 1;
        #pragma unroll
        for (int q = 0; q < 16; q++){
            const int i = (q & 3) + 8*(q >> 2) + 4*(lane >> 5);
            outp[(size_t)(rt0 + i) * CDIM + h*HD + cg*32 + (lane & 31)] = accB32[gg][q];
        }
    }
}

// ---------------------------------------------------------------------------
// final: dg[n][d] = sum_c beta[c/64]*dQb[n][c]*Wq[c][d] + dKh[n][c]*Wk[c][d]
// ---------------------------------------------------------------------------
__global__ __launch_bounds__(256) void final_dg_kernel(
    const float* __restrict__ dQbp, const float* __restrict__ dKhp,
    const float* __restrict__ Wq, const float* __restrict__ Wk,
    const float* __restrict__ betas, float* __restrict__ dg, int nseg)
{
    __shared__ float at[16][68];
    __shared__ float bt[16][68];
    const int n0 = blockIdx.x * 64, d0 = blockIdx.y * 64;
    const int t  = threadIdx.x;
    const int tx = t & 15, ty = t >> 4;
    const int lr = t >> 2, lk = (t & 3) * 4;
    float acc[4][4] = {};
    for (int src = 0; src < 2; src++){
        const float* P = src ? dKhp : dQbp;
        const float* W = src ? Wk  : Wq;
        for (int c0 = 0; c0 < CDIM; c0 += 16){
            __syncthreads();
            f32x4 a = {0.f,0.f,0.f,0.f};
            for (int s = 0; s < nseg; s++)
                a += *(const f32x4*)&P[((size_t)s * N_TOK + n0 + lr) * CDIM + c0 + lk];
            if (src == 0){
                const float bs = betas[(c0 + lk) >> 6];
                a *= bs;
            }
            at[lk+0][lr] = a[0]; at[lk+1][lr] = a[1]; at[lk+2][lr] = a[2]; at[lk+3][lr] = a[3];
            {
                const int kk = t >> 4, dd = (t & 15) * 4;
                f32x4 wv = *(const f32x4*)&W[(size_t)(c0 + kk) * DIM_IN + d0 + dd];
                bt[kk][dd+0] = wv[0]; bt[kk][dd+1] = wv[1]; bt[kk][dd+2] = wv[2]; bt[kk][dd+3] = wv[3];
            }
            __syncthreads();
            #pragma unroll
            for (int kk = 0; kk < 16; kk++){
                f32x4 av = *(const f32x4*)&at[kk][ty*4];
                f32x4 bv = *(const f32x4*)&bt[kk][tx*4];
                #pragma unroll
                for (int i = 0; i < 4; i++)
                    #pragma unroll
                    for (int j = 0; j < 4; j++)
                        acc[i][j] += av[i] * bv[j];
            }
        }
    }
    #pragma unroll
    for (int i = 0; i < 4; i++)
        #pragma unroll
        for (int j = 0; j < 4; j++)
            dg[(size_t)(n0 + ty*4 + i) * DIM_IN + d0 + tx*4 + j] = acc[i][j];
}

// ---------------------------------------------------------------------------
extern "C" void kernel_launch(void* const* d_in, const int* in_sizes, int n_in,
                              void* d_out, int out_size, void* d_ws, size_t ws_size,
                              hipStream_t stream)
{
    const float* g     = (const float*)d_in[0];
    const float* adj   = (const float*)d_in[1];
    const float* Wk    = (const float*)d_in[2];
    const float* Wq    = (const float*)d_in[3];
    const float* Hw    = (const float*)d_in[4];
    const float* Bk    = (const float*)d_in[5];
    const float* Bq    = (const float*)d_in[6];
    const float* betas = (const float*)d_in[7];
    float* out = (float*)d_out;

    char* ws = (char*)d_ws;
    const size_t szQb   = (size_t)N_TOK * CDIM * sizeof(unsigned short); // 6291456
    const size_t szL    = (size_t)N_TOK * NH * sizeof(float);            // 196608
    const size_t szPart = (size_t)N_TOK * CDIM * sizeof(float);          // 12582912

    unsigned short* Qb  = (unsigned short*)(ws);
    unsigned short* Kh  = (unsigned short*)(ws + szQb);
    unsigned short* QbT = (unsigned short*)(ws + 2*szQb);
    unsigned short* KhT = (unsigned short*)(ws + 3*szQb);
    float* l_ws   = (float*)(ws + 4*szQb);
    float* lse_ws = (float*)(ws + 4*szQb + szL);
    char*  parts  = ws + 4*szQb + 2*szL;
    const size_t base = 4*szQb + 2*szL;

    // KS=2: 256 bwd blocks = 1/CU (same work), and final_dg sums only 2
    // partial sets (halves its read traffic vs KS=4).
    int KS = (ws_size >= base + 4*szPart) ? 2 : 1;
    float* dQbp = (float*)parts;
    float* dKhp = (float*)(parts + (size_t)KS * szPart);

    hipMemsetAsync(l_ws, 0, szL, stream);
    hipMemsetAsync(d_out, 0, sizeof(float), stream);

    proj_kernel<<<dim3(64, 12), 256, 0, stream>>>(g, Wq, Bq, betas, Qb, QbT);
    proj_kernel<<<dim3(64, 12), 256, 0, stream>>>(g, Wk, Bk, nullptr, Kh, KhT);
    fwd_kernel<<<dim3(64, 8), 256, 0, stream>>>(Qb, Kh, adj, Hw, l_ws, N_TOK / 8);
    lse_energy_kernel<<<dim3(192), 256, 0, stream>>>(l_ws, lse_ws, betas, out);
    bwd_kernel<0><<<dim3(128, KS), 512, 0, stream>>>(Qb, Kh, KhT, adj, Hw, lse_ws, betas,
                                                     dQbp, N_TOK / KS);
    bwd_kernel<1><<<dim3(128, KS), 512, 0, stream>>>(Kh, Qb, QbT, adj, Hw, lse_ws, betas,
                                                     dKhp, N_TOK / KS);
    final_dg_kernel<<<dim3(64, 8), 256, 0, stream>>>(dQbp, dKhp, Wq, Wk, betas,
                                                     out + 1, KS);
}

// Round 7
// 1719.647 us; speedup vs baseline: 1.1102x; 1.1102x over previous
//
#include <hip/hip_runtime.h>
#include <stdint.h>

#define N_TOK 4096
#define DIM_IN 512
#define NH 12
#define HD 64
#define CDIM 768   // NH*HD

using f32x4  = __attribute__((ext_vector_type(4))) float;
using f32x16 = __attribute__((ext_vector_type(16))) float;
using bf16x8 = __attribute__((ext_vector_type(8))) short;

static __device__ __forceinline__ unsigned short f2bf(float f){
    union { float f; unsigned int u; } v; v.f = f;
    unsigned int r = v.u + 0x7fffu + ((v.u >> 16) & 1u);
    return (unsigned short)(r >> 16);
}

// ---------------------------------------------------------------------------
// proj: out[n][c] = (sum_d g[n][d]*W[c][d] + B[c]) * (scale ? scale[c/64] : 1)
// stored bf16 row-major (out) AND transposed (outT[c][n]).  outT written
// COALESCED via an LDS-staged tile transpose (r6's direct scatter was a
// stride-8KB store pattern -- regressed).
// ---------------------------------------------------------------------------
__global__ __launch_bounds__(256) void proj_kernel(
    const float* __restrict__ g, const float* __restrict__ W,
    const float* __restrict__ B, const float* __restrict__ scale,
    unsigned short* __restrict__ out, unsigned short* __restrict__ outT)
{
    __shared__ float at[16][68];
    __shared__ float bt[16][68];
    __shared__ unsigned short tbuf[64][72];   // 9216 B, 16B-aligned rows
    const int n0 = blockIdx.x * 64, c0 = blockIdx.y * 64;
    const int t  = threadIdx.x;
    const int tx = t & 15, ty = t >> 4;
    const int lr = t >> 2, lk = (t & 3) * 4;
    float acc[4][4] = {};
    for (int d0 = 0; d0 < DIM_IN; d0 += 16){
        __syncthreads();
        f32x4 gv = *(const f32x4*)&g[(size_t)(n0 + lr) * DIM_IN + d0 + lk];
        at[lk+0][lr] = gv[0]; at[lk+1][lr] = gv[1]; at[lk+2][lr] = gv[2]; at[lk+3][lr] = gv[3];
        f32x4 wv = *(const f32x4*)&W[(size_t)(c0 + lr) * DIM_IN + d0 + lk];
        bt[lk+0][lr] = wv[0]; bt[lk+1][lr] = wv[1]; bt[lk+2][lr] = wv[2]; bt[lk+3][lr] = wv[3];
        __syncthreads();
        #pragma unroll
        for (int kk = 0; kk < 16; kk++){
            f32x4 av = *(const f32x4*)&at[kk][ty*4];
            f32x4 bv = *(const f32x4*)&bt[kk][tx*4];
            #pragma unroll
            for (int i = 0; i < 4; i++)
                #pragma unroll
                for (int j = 0; j < 4; j++)
                    acc[i][j] += av[i] * bv[j];
        }
    }
    #pragma unroll
    for (int i = 0; i < 4; i++){
        const int n = n0 + ty*4 + i;
        #pragma unroll
        for (int j = 0; j < 4; j++){
            const int c = c0 + tx*4 + j;
            float v = acc[i][j] + B[c];
            if (scale) v *= scale[c >> 6];
            const unsigned short b = f2bf(v);
            out[(size_t)n * CDIM + c] = b;
            tbuf[tx*4+j][ty*4+i] = b;
        }
    }
    __syncthreads();
    // coalesced transposed write: thread t -> row c=t>>2, 16-elem seg (t&3)
    {
        const int cc = t >> 2, nn = (t & 3) * 16;
        bf16x8 v0 = *(const bf16x8*)&tbuf[cc][nn];
        bf16x8 v1 = *(const bf16x8*)&tbuf[cc][nn + 8];
        *(bf16x8*)&outT[(size_t)(c0 + cc) * N_TOK + n0 + nn]     = v0;
        *(bf16x8*)&outT[(size_t)(c0 + cc) * N_TOK + n0 + nn + 8] = v1;
    }
}

// ---------------------------------------------------------------------------
// forward (r5-verified form): kbuf LDS staging, per 16x16 (q,k) MFMA tile,
// 12 head scores -> Hw mix -> adj mask -> sum(exp) -> atomicAdd into l_ws.
// ---------------------------------------------------------------------------
#define TKF 32
#define KBS 776   // ushort stride: 1552 B (16B aligned, 2-way-bank only)

__global__ __launch_bounds__(256, 2) void fwd_kernel(
    const unsigned short* __restrict__ Qb, const unsigned short* __restrict__ Kh,
    const float* __restrict__ adj, const float* __restrict__ HwG,
    float* __restrict__ l_ws, int seg_len)
{
    __shared__ unsigned short kbuf[TKF][KBS];
    __shared__ float hw[NH][12];
    const int t = threadIdx.x;
    if (t < NH * 12) hw[t / 12][t % 12] = HwG[t];
    const int lane = t & 63, wave = t >> 6;
    const int quad = lane >> 4, col = lane & 15;
    const int qt0 = blockIdx.x * 64 + wave * 16;
    const int kstart = blockIdx.y * seg_len;

    bf16x8 af[NH][2];
    {
        const int arow = qt0 + col;
        #pragma unroll
        for (int h = 0; h < NH; h++)
            #pragma unroll
            for (int kk = 0; kk < 2; kk++)
                af[h][kk] = *(const bf16x8*)&Qb[(size_t)arow * CDIM + h*HD + kk*32 + quad*8];
    }
    f32x4 l4[4][3];
    #pragma unroll
    for (int r = 0; r < 4; r++)
        #pragma unroll
        for (int j = 0; j < 3; j++)
            l4[r][j] = (f32x4){0.f,0.f,0.f,0.f};

    for (int kc = kstart; kc < kstart + seg_len; kc += TKF){
        __syncthreads();
        #pragma unroll
        for (int i = 0; i < 12; i++){
            const int idx = t + 256 * i;
            const int row = idx / 96, cc = (idx % 96) * 8;
            *(bf16x8*)&kbuf[row][cc] = *(const bf16x8*)&Kh[(size_t)(kc + row) * CDIM + cc];
        }
        __syncthreads();
        #pragma unroll
        for (int sub = 0; sub < 2; sub++){
            const int k0 = kc + sub * 16;
            f32x4 tv[4][3];
            #pragma unroll
            for (int r = 0; r < 4; r++)
                #pragma unroll
                for (int j = 0; j < 3; j++)
                    tv[r][j] = (f32x4){0.f,0.f,0.f,0.f};
            #pragma unroll
            for (int h = 0; h < NH; h++){
                bf16x8 b0 = *(const bf16x8*)&kbuf[sub*16 + col][h*HD + quad*8];
                bf16x8 b1 = *(const bf16x8*)&kbuf[sub*16 + col][h*HD + 32 + quad*8];
                f32x4 s = {0.f,0.f,0.f,0.f};
                s = __builtin_amdgcn_mfma_f32_16x16x32_bf16(af[h][0], b0, s, 0, 0, 0);
                s = __builtin_amdgcn_mfma_f32_16x16x32_bf16(af[h][1], b1, s, 0, 0, 0);
                f32x4 w0 = *(const f32x4*)&hw[h][0];
                f32x4 w1 = *(const f32x4*)&hw[h][4];
                f32x4 w2 = *(const f32x4*)&hw[h][8];
                #pragma unroll
                for (int r = 0; r < 4; r++){
                    tv[r][0] += s[r] * w0;
                    tv[r][1] += s[r] * w1;
                    tv[r][2] += s[r] * w2;
                }
            }
            #pragma unroll
            for (int r = 0; r < 4; r++){
                const float adjv = adj[(size_t)(qt0 + quad*4 + r) * N_TOK + k0 + col];
                #pragma unroll
                for (int j = 0; j < 3; j++){
                    #pragma unroll
                    for (int c = 0; c < 4; c++){
                        const float mm = tv[r][j][c] * adjv;   // matches T*adj
                        if (mm != 0.f) l4[r][j][c] += __expf(mm);
                    }
                }
            }
        }
    }
    #pragma unroll
    for (int r = 0; r < 4; r++)
        #pragma unroll
        for (int j = 0; j < 3; j++)
            #pragma unroll
            for (int c = 0; c < 4; c++){
                float v = l4[r][j][c];
                v += __shfl_xor(v, 1, 16);
                v += __shfl_xor(v, 2, 16);
                v += __shfl_xor(v, 4, 16);
                v += __shfl_xor(v, 8, 16);
                if (col == j*4 + c)
                    atomicAdd(&l_ws[(size_t)(qt0 + quad*4 + r) * NH + (j*4 + c)], v);
            }
}

// ---------------------------------------------------------------------------
// lse + energy
// ---------------------------------------------------------------------------
__global__ __launch_bounds__(256) void lse_energy_kernel(
    const float* __restrict__ l_ws, float* __restrict__ lse_ws,
    const float* __restrict__ betas, float* __restrict__ energy)
{
    const int t = threadIdx.x;
    const int i = blockIdx.x * 256 + t;
    const float l = l_ws[i];
    float lse, ep;
    if (l > 0.f){ lse = logf(l); ep = -(1.f / betas[i % NH]) * lse; }
    else        { lse = -1e30f; ep = 0.f; }
    lse_ws[i] = lse;
    __shared__ float red[256];
    red[t] = ep;
    __syncthreads();
    for (int s = 128; s > 0; s >>= 1){
        if (t < s) red[t] += red[t + s];
        __syncthreads();
    }
    if (t == 0) atomicAdd(energy, red[0]);
}

// ---------------------------------------------------------------------------
// backward r7 = r5 structure (verified 503us) with ONE change:
// phase B B-operands come from colmatT (global, contiguous b128, L2-hot)
// instead of the colbuf u16 transpose gather.  Static LDS-pipe count for r5
// was ~11.5K cyc/chunk/block of 15.7K wall (~73% busy; gather alone 4.6K) --
// rocprof has no LDS-busy counter, this was the hidden bottleneck.  r6 proved
// phase-A/fwd LDS staging is load-bearing (global operands exposed L2 latency,
// -19%), so everything else stays r5.
// ---------------------------------------------------------------------------
#define CBS 776   // colbuf ushort stride

template<int MODE>
__global__ __attribute__((amdgpu_flat_work_group_size(512, 512), amdgpu_waves_per_eu(2, 2)))
void bwd_kernel(
    const unsigned short* __restrict__ rowmat, const unsigned short* __restrict__ colmat,
    const unsigned short* __restrict__ colmatT,
    const float* __restrict__ adj, const float* __restrict__ HwG,
    const float* __restrict__ lse_ws, const float* __restrict__ betas,
    float* __restrict__ out_part, int seg_len)
{
    __shared__ unsigned short colbuf[64][CBS];     // 99328 B
    __shared__ unsigned short dsbuf[NH][32][64];   // 49152 B
    __shared__ float adjbuf[32][68];               //  8704 B
    __shared__ float lsebuf[64 * NH];              //  3072 B (mode 1 only)
    __shared__ float rowlse[32 * NH];              //  1536 B (mode 0 only)
    __shared__ float invbuf[NH];                   //    48 B
    __shared__ float hw[NH][12];                   //   576 B
    const int t = threadIdx.x;
    if (t < NH * 12) hw[t / 12][t % 12] = HwG[t];
    if (t < NH) invbuf[t] = 1.f / betas[t];
    const int lane = t & 63, wave = t >> 6;
    const int quad = lane >> 4, col = lane & 15;
    const int rsub = wave >> 2, csub = wave & 3;
    const int n0 = csub * 16;
    const int rt0 = blockIdx.x * 32;
    const int rbase = rt0 + rsub * 16;       // this wave's 16 rows (phase A)
    const int cstart = blockIdx.y * seg_len;
    const int tA = n0 + col;

    if (MODE == 0 && t < 96)
        *(f32x4*)&rowlse[t*4] = *(const f32x4*)&lse_ws[(size_t)rt0 * NH + t*4];

    // A-fragment source row for this lane (16 B aligned vector loads)
    const unsigned short* rowp = &rowmat[(size_t)(rbase + col) * CDIM + quad*8];

    const int adj_m  = t >> 4, adj_nc = (t & 15) * 4;   // mode 0
    const int adj_qr = t >> 3, adj_kc = (t & 7) * 4;    // mode 1

    // ---- initial prefetch (chunk 0) ----
    bf16x8 pcol[12];
    f32x4  padj;
    f32x4  plse = {0.f,0.f,0.f,0.f};
    {
        const int cb = cstart;
        #pragma unroll
        for (int i = 0; i < 12; i++){
            const int idx = t + 512 * i;
            const int row = idx / 96, cc = (idx % 96) * 8;
            pcol[i] = *(const bf16x8*)&colmat[(size_t)(cb + row) * CDIM + cc];
        }
        if (MODE == 0) padj = *(const f32x4*)&adj[(size_t)(rt0 + adj_m) * N_TOK + cb + adj_nc];
        else           padj = *(const f32x4*)&adj[(size_t)(cb + adj_qr) * N_TOK + rt0 + adj_kc];
        if (MODE == 1 && t < 192)
            plse = *(const f32x4*)&lse_ws[(size_t)cb * NH + t*4];
    }

    f32x16 accB32[3];
    #pragma unroll
    for (int gg = 0; gg < 3; gg++)
        #pragma unroll
        for (int q = 0; q < 16; q++) accB32[gg][q] = 0.f;

    for (int cb = cstart; cb < cstart + seg_len; cb += 64){
        __syncthreads();
        // ---- write prefetched chunk into LDS ----
        #pragma unroll
        for (int i = 0; i < 12; i++){
            const int idx = t + 512 * i;
            const int row = idx / 96, cc = (idx % 96) * 8;
            // swizzled store: logical channel c lives at c ^ ((row>>3 & 3)<<3)
            *(bf16x8*)&colbuf[row][cc ^ (((row >> 3) & 3) << 3)] = pcol[i];
        }
        if (MODE == 0){
            adjbuf[adj_m][adj_nc+0] = padj[0]; adjbuf[adj_m][adj_nc+1] = padj[1];
            adjbuf[adj_m][adj_nc+2] = padj[2]; adjbuf[adj_m][adj_nc+3] = padj[3];
        } else {
            adjbuf[adj_kc+0][adj_qr] = padj[0]; adjbuf[adj_kc+1][adj_qr] = padj[1];
            adjbuf[adj_kc+2][adj_qr] = padj[2]; adjbuf[adj_kc+3][adj_qr] = padj[3];
        }
        if (MODE == 1 && t < 192)
            *(f32x4*)&lsebuf[t*4] = plse;
        __syncthreads();

        // launder the A-row pointer so the per-h loads below cannot be
        // hoisted out of the cb loop (would recreate a 96-reg af array)
        const unsigned short* rp = rowp;
        asm volatile("" : "+v"(rp));

        // ---- phase A: this wave's 16 rows x 16 cols (csub subtile) ----
        {
            const int swzA = ((tA >> 3) & 3) << 3;
            f32x4 G[4][3];
            #pragma unroll
            for (int r = 0; r < 4; r++)
                #pragma unroll
                for (int j = 0; j < 3; j++)
                    G[r][j] = (f32x4){0.f,0.f,0.f,0.f};
            #pragma unroll
            for (int h = 0; h < NH; h++){
                bf16x8 a0 = *(const bf16x8*)&rp[h*HD];
                bf16x8 a1 = *(const bf16x8*)&rp[h*HD + 32];
                bf16x8 b0 = *(const bf16x8*)&colbuf[tA][(h*HD + quad*8) ^ swzA];
                bf16x8 b1 = *(const bf16x8*)&colbuf[tA][(h*HD + 32 + quad*8) ^ swzA];
                f32x4 s = {0.f,0.f,0.f,0.f};
                s = __builtin_amdgcn_mfma_f32_16x16x32_bf16(a0, b0, s, 0, 0, 0);
                s = __builtin_amdgcn_mfma_f32_16x16x32_bf16(a1, b1, s, 0, 0, 0);
                f32x4 w0 = *(const f32x4*)&hw[h][0];
                f32x4 w1 = *(const f32x4*)&hw[h][4];
                f32x4 w2 = *(const f32x4*)&hw[h][8];
                #pragma unroll
                for (int r = 0; r < 4; r++){
                    G[r][0] += s[r] * w0;
                    G[r][1] += s[r] * w1;
                    G[r][2] += s[r] * w2;
                }
            }
            // t-values -> gradient G = -(1/b')*P   (lse + 1/beta from LDS)
            #pragma unroll
            for (int r = 0; r < 4; r++){
                const float adjv = adjbuf[rsub*16 + quad*4 + r][tA];
                #pragma unroll
                for (int j = 0; j < 3; j++){
                    f32x4 lv;
                    if (MODE == 0) lv = *(const f32x4*)&rowlse[(rsub*16 + quad*4 + r) * NH + j*4];
                    else           lv = *(const f32x4*)&lsebuf[tA * NH + j*4];
                    #pragma unroll
                    for (int c = 0; c < 4; c++){
                        const float mm = G[r][j][c] * adjv;
                        const float p  = (mm != 0.f) ? __expf(mm - lv[c]) : 0.f;
                        G[r][j][c] = -invbuf[j*4 + c] * p;
                    }
                }
            }
            // dS = G @ Hw^T, bf16 into dsbuf (swizzled: kk' = kk ^ ((m&7)<<3))
            #pragma unroll
            for (int h = 0; h < NH; h++){
                f32x4 w0 = *(const f32x4*)&hw[h][0];
                f32x4 w1 = *(const f32x4*)&hw[h][4];
                f32x4 w2 = *(const f32x4*)&hw[h][8];
                #pragma unroll
                for (int r = 0; r < 4; r++){
                    f32x4 pr = G[r][0]*w0 + G[r][1]*w1 + G[r][2]*w2;
                    const float d = pr[0] + pr[1] + pr[2] + pr[3];
                    const int m = rsub*16 + quad*4 + r;
                    dsbuf[h][m][tA ^ ((m & 7) << 3)] = f2bf(d);
                }
            }
        }

        // ---- issue prefetch of chunk t+1 (hides under phase B) ----
        {
            const int nxt = cb + 64;
            const int cbn = (nxt < cstart + seg_len) ? nxt : cstart;  // clamp (discarded)
            #pragma unroll
            for (int i = 0; i < 12; i++){
                const int idx = t + 512 * i;
                const int row = idx / 96, cc = (idx % 96) * 8;
                pcol[i] = *(const bf16x8*)&colmat[(size_t)(cbn + row) * CDIM + cc];
            }
            if (MODE == 0) padj = *(const f32x4*)&adj[(size_t)(rt0 + adj_m) * N_TOK + cbn + adj_nc];
            else           padj = *(const f32x4*)&adj[(size_t)(cbn + adj_qr) * N_TOK + rt0 + adj_kc];
            if (MODE == 1 && t < 192)
                plse = *(const f32x4*)&lse_ws[(size_t)cbn * NH + t*4];
        }
        __syncthreads();

        // ---- phase B (32x32x16): dRow[m][z] += sum_kk dS[m][kk]*colmat[kk][z]
        // B-operand from colmatT: contiguous b128 (the u16 gather is GONE).
        {
            const int mB = lane & 31;
            const int halfB = lane >> 5;
            #pragma unroll
            for (int gg = 0; gg < 3; gg++){
                const int gidx = wave + gg*8;
                const int h = gidx >> 1, cg = gidx & 1;
                const unsigned short* bpT =
                    &colmatT[(size_t)(h*HD + cg*32 + mB) * N_TOK + cb + halfB*8];
                f32x16 acc = accB32[gg];
                #pragma unroll
                for (int k0 = 0; k0 < 64; k0 += 16){
                    const int kbase = k0 + halfB*8;
                    bf16x8 a = *(const bf16x8*)&dsbuf[h][mB][kbase ^ ((mB & 7) << 3)];
                    bf16x8 b = *(const bf16x8*)&bpT[k0];
                    acc = __builtin_amdgcn_mfma_f32_32x32x16_bf16(a, b, acc, 0, 0, 0);
                }
                accB32[gg] = acc;
            }
        }
    }
    // ---- write dRow partials (32x32 D layout, r5-verified) ----
    float* outp = out_part + (size_t)blockIdx.y * N_TOK * CDIM;
    #pragma unroll
    for (int gg = 0; gg < 3; gg++){
        const int gidx = wave + gg*8;
        const int h = gidx >> 1, cg = gidx & 1;
        #pragma unroll
        for (int q = 0; q < 16; q++){
            const int i = (q & 3) + 8*(q >> 2) + 4*(lane >> 5);
            outp[(size_t)(rt0 + i) * CDIM + h*HD + cg*32 + (lane & 31)] = accB32[gg][q];
        }
    }
}

// ---------------------------------------------------------------------------
// final: dg[n][d] = sum_c beta[c/64]*dQb[n][c]*Wq[c][d] + dKh[n][c]*Wk[c][d]
// ---------------------------------------------------------------------------
__global__ __launch_bounds__(256) void final_dg_kernel(
    const float* __restrict__ dQbp, const float* __restrict__ dKhp,
    const float* __restrict__ Wq, const float* __restrict__ Wk,
    const float* __restrict__ betas, float* __restrict__ dg, int nseg)
{
    __shared__ float at[16][68];
    __shared__ float bt[16][68];
    const int n0 = blockIdx.x * 64, d0 = blockIdx.y * 64;
    const int t  = threadIdx.x;
    const int tx = t & 15, ty = t >> 4;
    const int lr = t >> 2, lk = (t & 3) * 4;
    float acc[4][4] = {};
    for (int src = 0; src < 2; src++){
        const float* P = src ? dKhp : dQbp;
        const float* W = src ? Wk  : Wq;
        for (int c0 = 0; c0 < CDIM; c0 += 16){
            __syncthreads();
            f32x4 a = {0.f,0.f,0.f,0.f};
            for (int s = 0; s < nseg; s++)
                a += *(const f32x4*)&P[((size_t)s * N_TOK + n0 + lr) * CDIM + c0 + lk];
            if (src == 0){
                const float bs = betas[(c0 + lk) >> 6];
                a *= bs;
            }
            at[lk+0][lr] = a[0]; at[lk+1][lr] = a[1]; at[lk+2][lr] = a[2]; at[lk+3][lr] = a[3];
            {
                const int kk = t >> 4, dd = (t & 15) * 4;
                f32x4 wv = *(const f32x4*)&W[(size_t)(c0 + kk) * DIM_IN + d0 + dd];
                bt[kk][dd+0] = wv[0]; bt[kk][dd+1] = wv[1]; bt[kk][dd+2] = wv[2]; bt[kk][dd+3] = wv[3];
            }
            __syncthreads();
            #pragma unroll
            for (int kk = 0; kk < 16; kk++){
                f32x4 av = *(const f32x4*)&at[kk][ty*4];
                f32x4 bv = *(const f32x4*)&bt[kk][tx*4];
                #pragma unroll
                for (int i = 0; i < 4; i++)
                    #pragma unroll
                    for (int j = 0; j < 4; j++)
                        acc[i][j] += av[i] * bv[j];
            }
        }
    }
    #pragma unroll
    for (int i = 0; i < 4; i++)
        #pragma unroll
        for (int j = 0; j < 4; j++)
            dg[(size_t)(n0 + ty*4 + i) * DIM_IN + d0 + tx*4 + j] = acc[i][j];
}

// ---------------------------------------------------------------------------
extern "C" void kernel_launch(void* const* d_in, const int* in_sizes, int n_in,
                              void* d_out, int out_size, void* d_ws, size_t ws_size,
                              hipStream_t stream)
{
    const float* g     = (const float*)d_in[0];
    const float* adj   = (const float*)d_in[1];
    const float* Wk    = (const float*)d_in[2];
    const float* Wq    = (const float*)d_in[3];
    const float* Hw    = (const float*)d_in[4];
    const float* Bk    = (const float*)d_in[5];
    const float* Bq    = (const float*)d_in[6];
    const float* betas = (const float*)d_in[7];
    float* out = (float*)d_out;

    char* ws = (char*)d_ws;
    const size_t szQb   = (size_t)N_TOK * CDIM * sizeof(unsigned short); // 6291456
    const size_t szL    = (size_t)N_TOK * NH * sizeof(float);            // 196608
    const size_t szPart = (size_t)N_TOK * CDIM * sizeof(float);          // 12582912

    unsigned short* Qb  = (unsigned short*)(ws);
    unsigned short* Kh  = (unsigned short*)(ws + szQb);
    unsigned short* QbT = (unsigned short*)(ws + 2*szQb);
    unsigned short* KhT = (unsigned short*)(ws + 3*szQb);
    float* l_ws   = (float*)(ws + 4*szQb);
    float* lse_ws = (float*)(ws + 4*szQb + szL);
    char*  parts  = ws + 4*szQb + 2*szL;
    const size_t base = 4*szQb + 2*szL;

    int KS = 1;
    if      (ws_size >= base + 8*szPart) KS = 4;
    else if (ws_size >= base + 4*szPart) KS = 2;
    float* dQbp = (float*)parts;
    float* dKhp = (float*)(parts + (size_t)KS * szPart);

    hipMemsetAsync(l_ws, 0, szL, stream);
    hipMemsetAsync(d_out, 0, sizeof(float), stream);

    proj_kernel<<<dim3(64, 12), 256, 0, stream>>>(g, Wq, Bq, betas, Qb, QbT);
    proj_kernel<<<dim3(64, 12), 256, 0, stream>>>(g, Wk, Bk, nullptr, Kh, KhT);
    fwd_kernel<<<dim3(64, 8), 256, 0, stream>>>(Qb, Kh, adj, Hw, l_ws, N_TOK / 8);
    lse_energy_kernel<<<dim3(192), 256, 0, stream>>>(l_ws, lse_ws, betas, out);
    bwd_kernel<0><<<dim3(128, KS), 512, 0, stream>>>(Qb, Kh, KhT, adj, Hw, lse_ws, betas,
                                                     dQbp, N_TOK / KS);
    bwd_kernel<1><<<dim3(128, KS), 512, 0, stream>>>(Kh, Qb, QbT, adj, Hw, lse_ws, betas,
                                                     dKhp, N_TOK / KS);
    final_dg_kernel<<<dim3(64, 8), 256, 0, stream>>>(dQbp, dKhp, Wq, Wk, betas,
                                                     out + 1, KS);
}